// Round 10
// baseline (732.729 us; speedup 1.0000x reference)
//
#include <hip/hip_runtime.h>
#include <stdint.h>

typedef __attribute__((ext_vector_type(8))) __bf16 bf16x8;
typedef __attribute__((ext_vector_type(4))) float f32x4;
typedef __attribute__((ext_vector_type(4))) unsigned int u32x4;

constexpr int B = 8, S = 1024, D = 512, H = 8, DFF = 2048, L = 4, DK = 64;
constexpr int MR = B * S;  // 8192 rows

__device__ __forceinline__ unsigned short f2bf(float f) {
    union { float f; unsigned u; } v; v.f = f;
    unsigned u = v.u;
    u += 0x7fffu + ((u >> 16) & 1u);   // RNE
    return (unsigned short)(u >> 16);
}

__device__ __forceinline__ void gload_lds16(const void* g, void* l) {
    __builtin_amdgcn_global_load_lds(
        (const __attribute__((address_space(1))) void*)g,
        (__attribute__((address_space(3))) void*)l, 16, 0, 0);
}

// ---------------- x = qe + pe ; y = qa + pe (f32 + bf16 copies) ----------------
__global__ __launch_bounds__(256) void add_pe_kernel(
    const float* __restrict__ qe, const float* __restrict__ qa,
    const float* __restrict__ pe, float* __restrict__ x_f32,
    unsigned short* __restrict__ x_bf, unsigned short* __restrict__ y_bf) {
    int gid = blockIdx.x * 256 + threadIdx.x;
    int base = gid * 4;
    int po = base & (S * D - 1);
    float4 p = *(const float4*)(pe + po);
    float4 a = *(const float4*)(qe + base);
    float4 q = *(const float4*)(qa + base);
    float4 xv = make_float4(a.x + p.x, a.y + p.y, a.z + p.z, a.w + p.w);
    float4 yv = make_float4(q.x + p.x, q.y + p.y, q.z + p.z, q.w + p.w);
    *(float4*)(x_f32 + base) = xv;
    ushort4 xb; xb.x = f2bf(xv.x); xb.y = f2bf(xv.y); xb.z = f2bf(xv.z); xb.w = f2bf(xv.w);
    ushort4 yb; yb.x = f2bf(yv.x); yb.y = f2bf(yv.y); yb.z = f2bf(yv.z); yb.w = f2bf(yv.w);
    *(ushort4*)(x_bf + base) = xb;
    *(ushort4*)(y_bf + base) = yb;
}

// ---------------- weight prep: f32 [K,N] -> bf16 [N,K], per layer (blockIdx.z) ----------------
__global__ __launch_bounds__(256) void wtrans_kernel(
    const float* __restrict__ src, unsigned short* __restrict__ dst, int K, int N) {
    __shared__ float t[64][65];
    src += (size_t)blockIdx.z * K * N;
    dst += (size_t)blockIdx.z * K * N;
    int n0 = blockIdx.x * 64, k0 = blockIdx.y * 64;
    int tid = threadIdx.x;
    int r = tid >> 4, c4 = (tid & 15) * 4;
    #pragma unroll
    for (int rr = 0; rr < 64; rr += 16) {
        float4 v = *(const float4*)(src + (size_t)(k0 + r + rr) * N + n0 + c4);
        t[r + rr][c4] = v.x; t[r + rr][c4 + 1] = v.y;
        t[r + rr][c4 + 2] = v.z; t[r + rr][c4 + 3] = v.w;
    }
    __syncthreads();
    int n = tid >> 2, kc = (tid & 3) * 16;
    ushort4 o[4];
    #pragma unroll
    for (int g = 0; g < 4; g++) {
        o[g].x = f2bf(t[kc + g * 4 + 0][n]);
        o[g].y = f2bf(t[kc + g * 4 + 1][n]);
        o[g].z = f2bf(t[kc + g * 4 + 2][n]);
        o[g].w = f2bf(t[kc + g * 4 + 3][n]);
    }
    unsigned short* dp = dst + (size_t)(n0 + n) * K + k0 + kc;
    #pragma unroll
    for (int g = 0; g < 4; g++) *(ushort4*)(dp + g * 4) = o[g];
}

// ---------------- GEMM: out = act(A[M,K](bf16) @ Bt[N,K](bf16)^T + bias [+resid]) ----------------
// Round-4 configuration (session best, 704.5us): single-buffered 128-tile,
// width-16 global_load_lds, XOR k-group swizzle, direct epilogues.
// Rounds 5-9 tested: dbuf+counted-vmcnt (regressed: LDS doubling halved
// occupancy), bounce epilogues (neutral-to-negative in clean A/B), 256-tile
// 4-phase FFN1 (regressed: 2-deep buffer forces per-tile vmcnt(0) drain =
// structurally 2-phase, the null quadrant). This structure is at its
// documented ~350-450TF shape ceiling for K=512 GEMMs.
template<int BN, bool RELU, bool RESID, bool OUT_F32, bool OUT_BF16, bool OUT_VT>
__global__ __launch_bounds__(256) void gemm_kernel(
    const unsigned short* __restrict__ A, const unsigned short* __restrict__ Bt,
    const float* __restrict__ bias, const float* __restrict__ resid,
    float* __restrict__ out_f32, unsigned short* __restrict__ out_bf,
    int M, int N, int K) {
    constexpr int MT = (BN == 128) ? 4 : 2;
    constexpr int WROWS = (BN == 128) ? 64 : 32;
    constexpr int BRND = (BN == 128) ? 4 : 2;
    __shared__ unsigned short a_lds[128 * 64];
    __shared__ unsigned short b_lds[BN * 64];

    const int tid = threadIdx.x;
    const int lane = tid & 63, wid = tid >> 6;
    const int wm = (BN == 128) ? (wid >> 1) : wid;
    const int wn = (BN == 128) ? (wid & 1) : 0;
    const int l15 = lane & 15, quad = lane >> 4;
    // bijective XCD remap (grids are always multiples of 8 blocks, nmt=64)
    const int nmt = gridDim.x, nnt = gridDim.y;
    const int o_lin = blockIdx.y * nmt + blockIdx.x;     // dispatch-linear, XCD = o_lin%8
    const int xcd = o_lin & 7, oi = o_lin >> 3;
    const int mtile = xcd * (nmt >> 3) + oi / nnt;
    const int ntile = oi % nnt;
    const int m0 = mtile * 128, n0 = ntile * BN;

    f32x4 acc[MT][4];
    #pragma unroll
    for (int i = 0; i < MT; i++)
        #pragma unroll
        for (int j = 0; j < 4; j++) { f32x4 z = {0.f, 0.f, 0.f, 0.f}; acc[i][j] = z; }

    const unsigned short* aP[4];
    unsigned short* aL[4];
    #pragma unroll
    for (int j = 0; j < 4; j++) {
        int c = wid * 256 + j * 64 + lane;
        int r = c >> 3, slot = c & 7, kg = slot ^ (r & 7);
        aP[j] = A + (size_t)(m0 + r) * K + kg * 8;
        aL[j] = a_lds + (size_t)(wid * 256 + j * 64) * 8;   // uniform
    }
    const unsigned short* bP[BRND];
    unsigned short* bL[BRND];
    #pragma unroll
    for (int j = 0; j < BRND; j++) {
        int c = wid * (BRND * 64) + j * 64 + lane;
        int r = c >> 3, slot = c & 7, kg = slot ^ (r & 7);
        bP[j] = Bt + (size_t)(n0 + r) * K + kg * 8;
        bL[j] = b_lds + (size_t)(wid * (BRND * 64) + j * 64) * 8;   // uniform
    }

    for (int k0 = 0; k0 < K; k0 += 64) {
        #pragma unroll
        for (int j = 0; j < 4; j++) gload_lds16(aP[j] + k0, aL[j]);
        #pragma unroll
        for (int j = 0; j < BRND; j++) gload_lds16(bP[j] + k0, bL[j]);
        __syncthreads();

        bf16x8 af[MT][2], bfv[4][2];
        #pragma unroll
        for (int mt = 0; mt < MT; mt++) {
            int row = wm * WROWS + mt * 16 + l15;
            #pragma unroll
            for (int kh = 0; kh < 2; kh++)
                af[mt][kh] = *(const bf16x8*)&a_lds[row * 64 + (((kh * 4 + quad) ^ (row & 7)) * 8)];
        }
        #pragma unroll
        for (int nt = 0; nt < 4; nt++) {
            int row = wn * 64 + nt * 16 + l15;
            #pragma unroll
            for (int kh = 0; kh < 2; kh++)
                bfv[nt][kh] = *(const bf16x8*)&b_lds[row * 64 + (((kh * 4 + quad) ^ (row & 7)) * 8)];
        }
        #pragma unroll
        for (int mt = 0; mt < MT; mt++)
            #pragma unroll
            for (int nt = 0; nt < 4; nt++) {
                acc[mt][nt] = __builtin_amdgcn_mfma_f32_16x16x32_bf16(af[mt][0], bfv[nt][0], acc[mt][nt], 0, 0, 0);
                acc[mt][nt] = __builtin_amdgcn_mfma_f32_16x16x32_bf16(af[mt][1], bfv[nt][1], acc[mt][nt], 0, 0, 0);
            }
        __syncthreads();
    }

    #pragma unroll
    for (int nt = 0; nt < 4; nt++) {
        int col = n0 + wn * 64 + nt * 16 + l15;
        float bv = bias[col];
        #pragma unroll
        for (int mt = 0; mt < MT; mt++) {
            int row0 = m0 + wm * WROWS + mt * 16 + quad * 4;
            if (OUT_VT) {
                int hh = col >> 6, d = col & 63;
                int bb = row0 >> 10, s0 = row0 & 1023;
                ushort4 o;
                o.x = f2bf(acc[mt][nt][0] + bv);
                o.y = f2bf(acc[mt][nt][1] + bv);
                o.z = f2bf(acc[mt][nt][2] + bv);
                o.w = f2bf(acc[mt][nt][3] + bv);
                *(ushort4*)(out_bf + ((size_t)(bb * H + hh) * DK + d) * S + s0) = o;
            } else {
                #pragma unroll
                for (int r = 0; r < 4; r++) {
                    int row = row0 + r;
                    float v = acc[mt][nt][r] + bv;
                    if (RESID) v += resid[(size_t)row * N + col];
                    if (RELU) v = fmaxf(v, 0.f);
                    size_t o = (size_t)row * N + col;
                    if (OUT_F32) out_f32[o] = v;
                    if (OUT_BF16) out_bf[o] = f2bf(v);
                }
            }
        }
    }
}

// ---------------- fused QK + V GEMM (z=0: qk row-major bf16; z=1: v transposed) --------
__global__ __launch_bounds__(256) void gemm_qkv_kernel(
    const unsigned short* __restrict__ x_bf, const unsigned short* __restrict__ y_bf,
    const unsigned short* __restrict__ wkT, const unsigned short* __restrict__ wvT,
    const float* __restrict__ bk, const float* __restrict__ bv,
    unsigned short* __restrict__ qk_out, unsigned short* __restrict__ vt_out) {
    constexpr int BN = 64, MT = 2, WROWS = 32, BRND = 2;
    constexpr int N = 512, K = 512;
    __shared__ unsigned short a_lds[128 * 64];
    __shared__ unsigned short b_lds[BN * 64];

    const bool isv = blockIdx.z != 0;
    const unsigned short* A  = isv ? y_bf : x_bf;
    const unsigned short* Bt = isv ? wvT : wkT;
    const float* bias        = isv ? bv : bk;

    const int tid = threadIdx.x;
    const int lane = tid & 63, wid = tid >> 6;
    const int l15 = lane & 15, quad = lane >> 4;
    const int nmt = gridDim.x, nnt = gridDim.y;
    const int o_lin = blockIdx.y * nmt + blockIdx.x;
    const int xcd = o_lin & 7, oi = o_lin >> 3;
    const int mtile = xcd * (nmt >> 3) + oi / nnt;
    const int ntile = oi % nnt;
    const int m0 = mtile * 128, n0 = ntile * BN;

    f32x4 acc[MT][4];
    #pragma unroll
    for (int i = 0; i < MT; i++)
        #pragma unroll
        for (int j = 0; j < 4; j++) { f32x4 z = {0.f, 0.f, 0.f, 0.f}; acc[i][j] = z; }

    const unsigned short* aP[4];
    unsigned short* aL[4];
    #pragma unroll
    for (int j = 0; j < 4; j++) {
        int c = wid * 256 + j * 64 + lane;
        int r = c >> 3, slot = c & 7, kg = slot ^ (r & 7);
        aP[j] = A + (size_t)(m0 + r) * K + kg * 8;
        aL[j] = a_lds + (size_t)(wid * 256 + j * 64) * 8;
    }
    const unsigned short* bP[BRND];
    unsigned short* bL[BRND];
    #pragma unroll
    for (int j = 0; j < BRND; j++) {
        int c = wid * (BRND * 64) + j * 64 + lane;
        int r = c >> 3, slot = c & 7, kg = slot ^ (r & 7);
        bP[j] = Bt + (size_t)(n0 + r) * K + kg * 8;
        bL[j] = b_lds + (size_t)(wid * (BRND * 64) + j * 64) * 8;
    }

    for (int k0 = 0; k0 < K; k0 += 64) {
        #pragma unroll
        for (int j = 0; j < 4; j++) gload_lds16(aP[j] + k0, aL[j]);
        #pragma unroll
        for (int j = 0; j < BRND; j++) gload_lds16(bP[j] + k0, bL[j]);
        __syncthreads();

        bf16x8 af[MT][2], bfv[4][2];
        #pragma unroll
        for (int mt = 0; mt < MT; mt++) {
            int row = wid * WROWS + mt * 16 + l15;
            #pragma unroll
            for (int kh = 0; kh < 2; kh++)
                af[mt][kh] = *(const bf16x8*)&a_lds[row * 64 + (((kh * 4 + quad) ^ (row & 7)) * 8)];
        }
        #pragma unroll
        for (int nt = 0; nt < 4; nt++) {
            int row = nt * 16 + l15;
            #pragma unroll
            for (int kh = 0; kh < 2; kh++)
                bfv[nt][kh] = *(const bf16x8*)&b_lds[row * 64 + (((kh * 4 + quad) ^ (row & 7)) * 8)];
        }
        #pragma unroll
        for (int mt = 0; mt < MT; mt++)
            #pragma unroll
            for (int nt = 0; nt < 4; nt++) {
                acc[mt][nt] = __builtin_amdgcn_mfma_f32_16x16x32_bf16(af[mt][0], bfv[nt][0], acc[mt][nt], 0, 0, 0);
                acc[mt][nt] = __builtin_amdgcn_mfma_f32_16x16x32_bf16(af[mt][1], bfv[nt][1], acc[mt][nt], 0, 0, 0);
            }
        __syncthreads();
    }

    #pragma unroll
    for (int nt = 0; nt < 4; nt++) {
        int col = n0 + nt * 16 + l15;
        float bv_ = bias[col];
        #pragma unroll
        for (int mt = 0; mt < MT; mt++) {
            int row0 = m0 + wid * WROWS + mt * 16 + quad * 4;
            ushort4 o;
            o.x = f2bf(acc[mt][nt][0] + bv_);
            o.y = f2bf(acc[mt][nt][1] + bv_);
            o.z = f2bf(acc[mt][nt][2] + bv_);
            o.w = f2bf(acc[mt][nt][3] + bv_);
            if (isv) {
                int hh = col >> 6, d = col & 63;
                int bb = row0 >> 10, s0 = row0 & 1023;
                *(ushort4*)(vt_out + ((size_t)(bb * H + hh) * DK + d) * S + s0) = o;
            } else {
                #pragma unroll
                for (int r = 0; r < 4; r++)
                    qk_out[(size_t)(row0 + r) * N + col] =
                        (r == 0) ? o.x : (r == 1) ? o.y : (r == 2) ? o.z : o.w;
            }
        }
    }
}

// ---------------- LayerNorm over D=512, one block per row ----------------
__global__ __launch_bounds__(256) void ln_kernel(
    const float* __restrict__ in, const float* __restrict__ gamma,
    const float* __restrict__ beta, float* __restrict__ out_f32,
    unsigned short* __restrict__ out_bf) {
    __shared__ float red[8];
    int row = blockIdx.x, tid = threadIdx.x;
    const float* p = in + (size_t)row * D;
    float2 v = *(const float2*)(p + tid * 2);
    float s = v.x + v.y;
    float q = v.x * v.x + v.y * v.y;
    #pragma unroll
    for (int off = 32; off > 0; off >>= 1) {
        s += __shfl_xor(s, off);
        q += __shfl_xor(q, off);
    }
    int wid = tid >> 6, lane = tid & 63;
    if (lane == 0) { red[wid] = s; red[4 + wid] = q; }
    __syncthreads();
    s = red[0] + red[1] + red[2] + red[3];
    q = red[4] + red[5] + red[6] + red[7];
    float mean = s * (1.f / D);
    float var = q * (1.f / D) - mean * mean;
    float inv = rsqrtf(var + 1e-5f);
    int c = tid * 2;
    float2 g = *(const float2*)(gamma + c);
    float2 bb = *(const float2*)(beta + c);
    float o0 = (v.x - mean) * inv * g.x + bb.x;
    float o1 = (v.y - mean) * inv * g.y + bb.y;
    *(float2*)(out_f32 + (size_t)row * D + c) = make_float2(o0, o1);
    ushort2 ob; ob.x = f2bf(o0); ob.y = f2bf(o1);
    *(ushort2*)(out_bf + (size_t)row * D + c) = ob;
}

// ---------------- Flash attention: 4-wave blocks, LDS-shared K/V, no split-K --------
__global__ __launch_bounds__(256, 2) void attn_kernel(
    const unsigned short* __restrict__ qk, const unsigned short* __restrict__ vt,
    unsigned short* __restrict__ ob) {
    __shared__ unsigned short kbuf[2][64 * 64];
    __shared__ unsigned short vbuf[2][64 * 64];
    __shared__ unsigned p_u32[4][32 * 36];     // per-wave P (32 dwords + 4 pad per row)
    constexpr float C = 0.18033688011112042f;  // log2(e)/8
    const float NEGINF = -__builtin_huge_valf();

    const int bx = blockIdx.x;
    const int Qb = 7 - (bx >> 6);              // heavy q-blocks first
    const int hh = bx & 63;
    const int b = hh >> 3, h = hh & 7;         // XCD = bx%8 = h -> 2MB K/V set per XCD
    const int head = hh;
    const int tid = threadIdx.x;
    const int w = tid >> 6, lane = tid & 63;
    const int l15 = lane & 15, quad = lane >> 4;

    const int nkt = 2 * Qb + 2;                // causal k-tiles for this q-block
    const int qrow0 = Qb * 128 + w * 32;       // wave's first q-row

    const int rowbase = b * S, colbase = h * DK;
    const unsigned short* kbase = qk + (size_t)rowbase * D + colbase;
    const unsigned short* vbase = vt + (size_t)head * (DK * S);

    bf16x8 qf[2][2];
    #pragma unroll
    for (int u = 0; u < 2; u++) {
        const unsigned short* qrow =
            qk + (size_t)(rowbase + qrow0 + u * 16 + l15) * D + colbase;
        qf[u][0] = *(const bf16x8*)(qrow + quad * 8);
        qf[u][1] = *(const bf16x8*)(qrow + 32 + quad * 8);
    }

    // staging lane map: 8 lanes/row, XOR-swizzled source seg so LDS stays linear
    const int sr = lane >> 3;
    const int sseg = (lane & 7) ^ sr;
    const unsigned short* kgp[2]; const unsigned short* vgp[2];
    unsigned short* kld[2]; unsigned short* vld[2];
    #pragma unroll
    for (int j = 0; j < 2; j++) {
        int rt = w * 16 + j * 8 + sr;
        kgp[j] = kbase + (size_t)rt * D + sseg * 8;
        vgp[j] = vbase + (size_t)rt * S + sseg * 8;
        kld[j] = &kbuf[0][(w * 16 + j * 8) * 64];   // wave-uniform
        vld[j] = &vbuf[0][(w * 16 + j * 8) * 64];
    }
    auto stage = [&](int buf, int kt) {
        #pragma unroll
        for (int j = 0; j < 2; j++) gload_lds16(kgp[j] + (size_t)kt * 64 * D, kld[j] + buf * 4096);
        #pragma unroll
        for (int j = 0; j < 2; j++) gload_lds16(vgp[j] + kt * 64, vld[j] + buf * 4096);
    };

    float l_r[2] = {0.f, 0.f};
    f32x4 o_acc[2][4];
    #pragma unroll
    for (int u = 0; u < 2; u++)
        #pragma unroll
        for (int i = 0; i < 4; i++) { f32x4 z = {0.f, 0.f, 0.f, 0.f}; o_acc[u][i] = z; }

    auto consume = [&](int kt, const unsigned short* kl, const unsigned short* vl) {
        unsigned* pb = p_u32[w];
        bf16x8 kf[4][2];
        #pragma unroll
        for (int mt = 0; mt < 4; mt++) {
            const unsigned short* kr = kl + (mt * 16 + l15) * 64;
            #pragma unroll
            for (int kh = 0; kh < 2; kh++)
                kf[mt][kh] = *(const bf16x8*)(kr + (((kh * 4 + quad) ^ (l15 & 7)) * 8));
        }
        const bool diag = kt * 64 + 64 > qrow0;
        #pragma unroll
        for (int u = 0; u < 2; u++) {
            const int qb = qrow0 + u * 16;
            const int ql = u * 16 + l15;
            #pragma unroll
            for (int mt = 0; mt < 4; mt++) {
                if (kt * 64 + mt * 16 < qb + 16) {
                    f32x4 a = {0.f, 0.f, 0.f, 0.f};
                    a = __builtin_amdgcn_mfma_f32_16x16x32_bf16(kf[mt][0], qf[u][0], a, 0, 0, 0);
                    a = __builtin_amdgcn_mfma_f32_16x16x32_bf16(kf[mt][1], qf[u][1], a, 0, 0, 0);
                    if (diag) {
                        const int gi = qb + l15;
                        #pragma unroll
                        for (int r = 0; r < 4; r++) {
                            int gj = kt * 64 + mt * 16 + quad * 4 + r;
                            a[r] = (gj >= gi) ? NEGINF : a[r];
                        }
                    }
                    float e0 = exp2f(a[0] * C), e1 = exp2f(a[1] * C);
                    float e2 = exp2f(a[2] * C), e3 = exp2f(a[3] * C);
                    unsigned pk0, pk1;
                    asm("v_cvt_pk_bf16_f32 %0, %1, %2" : "=v"(pk0) : "v"(e0), "v"(e1));
                    asm("v_cvt_pk_bf16_f32 %0, %1, %2" : "=v"(pk1) : "v"(e2), "v"(e3));
                    l_r[u] += (e0 + e1) + (e2 + e3);
                    *(uint2*)&pb[ql * 36 + mt * 8 + quad * 2] = make_uint2(pk0, pk1);
                } else {
                    *(uint2*)&pb[ql * 36 + mt * 8 + quad * 2] = make_uint2(0u, 0u);
                }
            }
        }
        bf16x8 vf[4][2];
        #pragma unroll
        for (int mt = 0; mt < 4; mt++) {
            const unsigned short* vr = vl + (mt * 16 + l15) * 64;
            #pragma unroll
            for (int kh = 0; kh < 2; kh++)
                vf[mt][kh] = *(const bf16x8*)(vr + (((kh * 4 + quad) ^ (l15 & 7)) * 8));
        }
        #pragma unroll
        for (int u = 0; u < 2; u++) {
            const int qb = qrow0 + u * 16;
            const int ql = u * 16 + l15;
            u32x4 d0 = *(const u32x4*)&pb[ql * 36 + quad * 4];
            bf16x8 pb0 = __builtin_bit_cast(bf16x8, d0);
            const bool hi = (kt * 64 + 32 < qb + 16);
            if (hi) {
                u32x4 d1 = *(const u32x4*)&pb[ql * 36 + 16 + quad * 4];
                bf16x8 pb1 = __builtin_bit_cast(bf16x8, d1);
                #pragma unroll
                for (int mt = 0; mt < 4; mt++) {
                    o_acc[u][mt] = __builtin_amdgcn_mfma_f32_16x16x32_bf16(vf[mt][0], pb0, o_acc[u][mt], 0, 0, 0);
                    o_acc[u][mt] = __builtin_amdgcn_mfma_f32_16x16x32_bf16(vf[mt][1], pb1, o_acc[u][mt], 0, 0, 0);
                }
            } else {
                #pragma unroll
                for (int mt = 0; mt < 4; mt++)
                    o_acc[u][mt] = __builtin_amdgcn_mfma_f32_16x16x32_bf16(vf[mt][0], pb0, o_acc[u][mt], 0, 0, 0);
            }
        }
    };

    stage(0, 0);
    for (int kt = 0; kt < nkt; ++kt) {
        const int cur = kt & 1;
        if (kt + 1 < nkt) {
            stage(cur ^ 1, kt + 1);
            asm volatile("s_waitcnt vmcnt(4)" ::: "memory");   // cur's 4 loads done, next 4 in flight
        } else {
            asm volatile("s_waitcnt vmcnt(0)" ::: "memory");
        }
        __builtin_amdgcn_sched_barrier(0);
        __builtin_amdgcn_s_barrier();
        __builtin_amdgcn_sched_barrier(0);
        if (kt * 64 < qrow0 + 32)              // skip fully-masked tiles (still barrier)
            consume(kt, &kbuf[cur][0], &vbuf[cur][0]);
        __builtin_amdgcn_sched_barrier(0);
        __builtin_amdgcn_s_barrier();          // all waves done reading before overwrite
        __builtin_amdgcn_sched_barrier(0);
    }

    // full-row l across quads, then write normalized bf16 O directly
    #pragma unroll
    for (int u = 0; u < 2; u++) {
        l_r[u] += __shfl_xor(l_r[u], 16);
        l_r[u] += __shfl_xor(l_r[u], 32);
    }
    #pragma unroll
    for (int u = 0; u < 2; u++) {
        const int si = qrow0 + u * 16 + l15;
        float inv = (l_r[u] > 0.f) ? 1.f / l_r[u] : 0.f;
        if (si == 0) inv = 0.f;   // row_keep
        unsigned short* orow = ob + (size_t)(b * S + si) * D + h * DK;
        #pragma unroll
        for (int mt = 0; mt < 4; mt++) {
            ushort4 o;
            o.x = f2bf(o_acc[u][mt][0] * inv);
            o.y = f2bf(o_acc[u][mt][1] * inv);
            o.z = f2bf(o_acc[u][mt][2] * inv);
            o.w = f2bf(o_acc[u][mt][3] * inv);
            *(ushort4*)(orow + mt * 16 + quad * 4) = o;
        }
    }
}

// ---------------- driver ----------------
extern "C" void kernel_launch(void* const* d_in, const int* in_sizes, int n_in,
                              void* d_out, int out_size, void* d_ws, size_t ws_size,
                              hipStream_t stream) {
    (void)in_sizes; (void)n_in; (void)out_size; (void)ws_size;
    const float* qe  = (const float*)d_in[0];
    const float* qa  = (const float*)d_in[1];
    const float* pe  = (const float*)d_in[2];
    const float* Wk  = (const float*)d_in[3];
    const float* bk  = (const float*)d_in[4];
    const float* Wv  = (const float*)d_in[5];
    const float* bv  = (const float*)d_in[6];
    const float* Wo  = (const float*)d_in[7];
    const float* bo  = (const float*)d_in[8];
    const float* l1s = (const float*)d_in[9];
    const float* l1b = (const float*)d_in[10];
    const float* W1  = (const float*)d_in[11];
    const float* b1  = (const float*)d_in[12];
    const float* W2  = (const float*)d_in[13];
    const float* b2  = (const float*)d_in[14];
    const float* l2s = (const float*)d_in[15];
    const float* l2b = (const float*)d_in[16];

    char* w = (char*)d_ws;
    float* x_f32  = (float*)w;           w += (size_t)MR * D * 4;
    float* t_f32  = (float*)w;           w += (size_t)MR * D * 4;
    float* x1_f32 = (float*)w;           w += (size_t)MR * D * 4;
    unsigned short* x_bf  = (unsigned short*)w; w += (size_t)MR * D * 2;
    unsigned short* y_bf  = (unsigned short*)w; w += (size_t)MR * D * 2;
    unsigned short* qk_bf = (unsigned short*)w; w += (size_t)MR * D * 2;
    unsigned short* vt_bf = (unsigned short*)w; w += (size_t)MR * D * 2;  // V^T [B,H,DK,S]
    unsigned short* o_bf  = (unsigned short*)w; w += (size_t)MR * D * 2;
    unsigned short* x1_bf = (unsigned short*)w; w += (size_t)MR * D * 2;
    unsigned short* h_bf  = (unsigned short*)w; w += (size_t)MR * DFF * 2;
    unsigned short* wkT = (unsigned short*)w;   w += (size_t)L * D * D * 2;
    unsigned short* wvT = (unsigned short*)w;   w += (size_t)L * D * D * 2;
    unsigned short* woT = (unsigned short*)w;   w += (size_t)L * D * D * 2;
    unsigned short* w1T = (unsigned short*)w;   w += (size_t)L * D * DFF * 2;
    unsigned short* w2T = (unsigned short*)w;   w += (size_t)L * DFF * D * 2;

    add_pe_kernel<<<MR * D / 4 / 256, 256, 0, stream>>>(qe, qa, pe, x_f32, x_bf, y_bf);
    wtrans_kernel<<<dim3(8, 8, L), 256, 0, stream>>>(Wk, wkT, D, D);
    wtrans_kernel<<<dim3(8, 8, L), 256, 0, stream>>>(Wv, wvT, D, D);
    wtrans_kernel<<<dim3(8, 8, L), 256, 0, stream>>>(Wo, woT, D, D);
    wtrans_kernel<<<dim3(32, 8, L), 256, 0, stream>>>(W1, w1T, D, DFF);
    wtrans_kernel<<<dim3(8, 32, L), 256, 0, stream>>>(W2, w2T, DFF, D);

    dim3 g512(64, 8), g2048(64, 16);
    for (int l = 0; l < L; l++) {
        gemm_qkv_kernel<<<dim3(64, 8, 2), 256, 0, stream>>>(
            x_bf, y_bf, wkT + (size_t)l * D * D, wvT + (size_t)l * D * D,
            bk + l * D, bv + l * D, qk_bf, vt_bf);
        attn_kernel<<<512, 256, 0, stream>>>(qk_bf, vt_bf, o_bf);
        gemm_kernel<64, false, true, true, false, false><<<g512, 256, 0, stream>>>(
            o_bf, woT + (size_t)l * D * D, bo + l * D, x_f32, t_f32, nullptr, MR, D, D);
        ln_kernel<<<MR, 256, 0, stream>>>(t_f32, l1s + l * D, l1b + l * D, x1_f32, x1_bf);
        gemm_kernel<128, true, false, false, true, false><<<g2048, 256, 0, stream>>>(
            x1_bf, w1T + (size_t)l * D * DFF, b1 + l * DFF, nullptr, nullptr, h_bf, MR, DFF, D);
        gemm_kernel<64, false, true, true, false, false><<<g512, 256, 0, stream>>>(
            h_bf, w2T + (size_t)l * DFF * D, b2 + l * D, x1_f32, t_f32, nullptr, MR, D, DFF);
        float* xo = (l == L - 1) ? (float*)d_out : x_f32;
        ln_kernel<<<MR, 256, 0, stream>>>(t_f32, l2s + l * D, l2b + l * D, xo, x_bf);
    }
}

// Round 11
// 703.305 us; speedup vs baseline: 1.0418x; 1.0418x over previous
//
#include <hip/hip_runtime.h>
#include <stdint.h>

typedef __attribute__((ext_vector_type(8))) __bf16 bf16x8;
typedef __attribute__((ext_vector_type(4))) float f32x4;
typedef __attribute__((ext_vector_type(4))) unsigned int u32x4;

constexpr int B = 8, S = 1024, D = 512, H = 8, DFF = 2048, L = 4, DK = 64;
constexpr int MR = B * S;  // 8192 rows

__device__ __forceinline__ unsigned short f2bf(float f) {
    union { float f; unsigned u; } v; v.f = f;
    unsigned u = v.u;
    u += 0x7fffu + ((u >> 16) & 1u);   // RNE
    return (unsigned short)(u >> 16);
}

__device__ __forceinline__ void gload_lds16(const void* g, void* l) {
    __builtin_amdgcn_global_load_lds(
        (const __attribute__((address_space(1))) void*)g,
        (__attribute__((address_space(3))) void*)l, 16, 0, 0);
}

// ---------------- x = qe + pe ; y = qa + pe (f32 + bf16 copies) ----------------
__global__ __launch_bounds__(256) void add_pe_kernel(
    const float* __restrict__ qe, const float* __restrict__ qa,
    const float* __restrict__ pe, float* __restrict__ x_f32,
    unsigned short* __restrict__ x_bf, unsigned short* __restrict__ y_bf) {
    int gid = blockIdx.x * 256 + threadIdx.x;
    int base = gid * 4;
    int po = base & (S * D - 1);
    float4 p = *(const float4*)(pe + po);
    float4 a = *(const float4*)(qe + base);
    float4 q = *(const float4*)(qa + base);
    float4 xv = make_float4(a.x + p.x, a.y + p.y, a.z + p.z, a.w + p.w);
    float4 yv = make_float4(q.x + p.x, q.y + p.y, q.z + p.z, q.w + p.w);
    *(float4*)(x_f32 + base) = xv;
    ushort4 xb; xb.x = f2bf(xv.x); xb.y = f2bf(xv.y); xb.z = f2bf(xv.z); xb.w = f2bf(xv.w);
    ushort4 yb; yb.x = f2bf(yv.x); yb.y = f2bf(yv.y); yb.z = f2bf(yv.z); yb.w = f2bf(yv.w);
    *(ushort4*)(x_bf + base) = xb;
    *(ushort4*)(y_bf + base) = yb;
}

// ---------------- weight prep: f32 [K,N] -> bf16 [N,K], per layer (blockIdx.z) ----------------
__global__ __launch_bounds__(256) void wtrans_kernel(
    const float* __restrict__ src, unsigned short* __restrict__ dst, int K, int N) {
    __shared__ float t[64][65];
    src += (size_t)blockIdx.z * K * N;
    dst += (size_t)blockIdx.z * K * N;
    int n0 = blockIdx.x * 64, k0 = blockIdx.y * 64;
    int tid = threadIdx.x;
    int r = tid >> 4, c4 = (tid & 15) * 4;
    #pragma unroll
    for (int rr = 0; rr < 64; rr += 16) {
        float4 v = *(const float4*)(src + (size_t)(k0 + r + rr) * N + n0 + c4);
        t[r + rr][c4] = v.x; t[r + rr][c4 + 1] = v.y;
        t[r + rr][c4 + 2] = v.z; t[r + rr][c4 + 3] = v.w;
    }
    __syncthreads();
    int n = tid >> 2, kc = (tid & 3) * 16;
    ushort4 o[4];
    #pragma unroll
    for (int g = 0; g < 4; g++) {
        o[g].x = f2bf(t[kc + g * 4 + 0][n]);
        o[g].y = f2bf(t[kc + g * 4 + 1][n]);
        o[g].z = f2bf(t[kc + g * 4 + 2][n]);
        o[g].w = f2bf(t[kc + g * 4 + 3][n]);
    }
    unsigned short* dp = dst + (size_t)(n0 + n) * K + k0 + kc;
    #pragma unroll
    for (int g = 0; g < 4; g++) *(ushort4*)(dp + g * 4) = o[g];
}

// ---------------- GEMM: out = act(A[M,K](bf16) @ Bt[N,K](bf16)^T + bias [+resid]) ----------------
template<int BN, bool RELU, bool RESID, bool OUT_F32, bool OUT_BF16, bool OUT_VT>
__global__ __launch_bounds__(256) void gemm_kernel(
    const unsigned short* __restrict__ A, const unsigned short* __restrict__ Bt,
    const float* __restrict__ bias, const float* __restrict__ resid,
    float* __restrict__ out_f32, unsigned short* __restrict__ out_bf,
    int M, int N, int K) {
    constexpr int MT = (BN == 128) ? 4 : 2;
    constexpr int WROWS = (BN == 128) ? 64 : 32;
    constexpr int BRND = (BN == 128) ? 4 : 2;
    __shared__ unsigned short a_lds[128 * 64];
    __shared__ unsigned short b_lds[BN * 64];

    const int tid = threadIdx.x;
    const int lane = tid & 63, wid = tid >> 6;
    const int wm = (BN == 128) ? (wid >> 1) : wid;
    const int wn = (BN == 128) ? (wid & 1) : 0;
    const int l15 = lane & 15, quad = lane >> 4;
    const int nmt = gridDim.x, nnt = gridDim.y;
    const int o_lin = blockIdx.y * nmt + blockIdx.x;
    const int xcd = o_lin & 7, oi = o_lin >> 3;
    const int mtile = xcd * (nmt >> 3) + oi / nnt;
    const int ntile = oi % nnt;
    const int m0 = mtile * 128, n0 = ntile * BN;

    f32x4 acc[MT][4];
    #pragma unroll
    for (int i = 0; i < MT; i++)
        #pragma unroll
        for (int j = 0; j < 4; j++) { f32x4 z = {0.f, 0.f, 0.f, 0.f}; acc[i][j] = z; }

    const unsigned short* aP[4];
    unsigned short* aL[4];
    #pragma unroll
    for (int j = 0; j < 4; j++) {
        int c = wid * 256 + j * 64 + lane;
        int r = c >> 3, slot = c & 7, kg = slot ^ (r & 7);
        aP[j] = A + (size_t)(m0 + r) * K + kg * 8;
        aL[j] = a_lds + (size_t)(wid * 256 + j * 64) * 8;   // uniform
    }
    const unsigned short* bP[BRND];
    unsigned short* bL[BRND];
    #pragma unroll
    for (int j = 0; j < BRND; j++) {
        int c = wid * (BRND * 64) + j * 64 + lane;
        int r = c >> 3, slot = c & 7, kg = slot ^ (r & 7);
        bP[j] = Bt + (size_t)(n0 + r) * K + kg * 8;
        bL[j] = b_lds + (size_t)(wid * (BRND * 64) + j * 64) * 8;   // uniform
    }

    for (int k0 = 0; k0 < K; k0 += 64) {
        #pragma unroll
        for (int j = 0; j < 4; j++) gload_lds16(aP[j] + k0, aL[j]);
        #pragma unroll
        for (int j = 0; j < BRND; j++) gload_lds16(bP[j] + k0, bL[j]);
        __syncthreads();

        bf16x8 af[MT][2], bfv[4][2];
        #pragma unroll
        for (int mt = 0; mt < MT; mt++) {
            int row = wm * WROWS + mt * 16 + l15;
            #pragma unroll
            for (int kh = 0; kh < 2; kh++)
                af[mt][kh] = *(const bf16x8*)&a_lds[row * 64 + (((kh * 4 + quad) ^ (row & 7)) * 8)];
        }
        #pragma unroll
        for (int nt = 0; nt < 4; nt++) {
            int row = wn * 64 + nt * 16 + l15;
            #pragma unroll
            for (int kh = 0; kh < 2; kh++)
                bfv[nt][kh] = *(const bf16x8*)&b_lds[row * 64 + (((kh * 4 + quad) ^ (row & 7)) * 8)];
        }
        #pragma unroll
        for (int mt = 0; mt < MT; mt++)
            #pragma unroll
            for (int nt = 0; nt < 4; nt++) {
                acc[mt][nt] = __builtin_amdgcn_mfma_f32_16x16x32_bf16(af[mt][0], bfv[nt][0], acc[mt][nt], 0, 0, 0);
                acc[mt][nt] = __builtin_amdgcn_mfma_f32_16x16x32_bf16(af[mt][1], bfv[nt][1], acc[mt][nt], 0, 0, 0);
            }
        __syncthreads();
    }

    #pragma unroll
    for (int nt = 0; nt < 4; nt++) {
        int col = n0 + wn * 64 + nt * 16 + l15;
        float bv = bias[col];
        #pragma unroll
        for (int mt = 0; mt < MT; mt++) {
            int row0 = m0 + wm * WROWS + mt * 16 + quad * 4;
            if (OUT_VT) {
                int hh = col >> 6, d = col & 63;
                int bb = row0 >> 10, s0 = row0 & 1023;
                ushort4 o;
                o.x = f2bf(acc[mt][nt][0] + bv);
                o.y = f2bf(acc[mt][nt][1] + bv);
                o.z = f2bf(acc[mt][nt][2] + bv);
                o.w = f2bf(acc[mt][nt][3] + bv);
                *(ushort4*)(out_bf + ((size_t)(bb * H + hh) * DK + d) * S + s0) = o;
            } else {
                #pragma unroll
                for (int r = 0; r < 4; r++) {
                    int row = row0 + r;
                    float v = acc[mt][nt][r] + bv;
                    if (RESID) v += resid[(size_t)row * N + col];
                    if (RELU) v = fmaxf(v, 0.f);
                    size_t o = (size_t)row * N + col;
                    if (OUT_F32) out_f32[o] = v;
                    if (OUT_BF16) out_bf[o] = f2bf(v);
                }
            }
        }
    }
}

// ---------------- FFN1: 256x256, BK=32, 3-deep LDS ring, counted vmcnt ----------------
// Round-9 failure diagnosed: 2-deep buffer forces vmcnt(0) on loads issued in the
// SAME tile (zero lead) = the null 2-phase quadrant. Fix: 3 buffers (BK=32 ->
// 3x32KB=96KB fits), stage tile t+3 while computing t, wait vmcnt(8) = tile t+1,
// issued 2 tiles (~500+cy) earlier. Never vmcnt(0) in the main loop.
// Geometry (wave grid 2Mx4N, acc[8][4], bounce epilogue) verified correct in r9.
__global__ __launch_bounds__(512, 2) void ffn1_kernel(
    const unsigned short* __restrict__ A, const unsigned short* __restrict__ Bt,
    const float* __restrict__ bias, unsigned short* __restrict__ out_bf) {
    constexpr int K = 512, N = 2048, NT = 16;
    __shared__ unsigned short lds[3 * 16384];   // 96KB: 3 x (A 256x32 | B 256x32)

    const int tid = threadIdx.x;
    const int lane = tid & 63, w = tid >> 6;
    const int wm = w >> 2, wn = w & 3;           // 2M x 4N wave grid, 128x64 out/wave
    const int l15 = lane & 15, quad = lane >> 4;
    const int nmt = gridDim.x, nnt = gridDim.y;  // 32, 8
    const int o_lin = blockIdx.y * nmt + blockIdx.x;
    const int xcd = o_lin & 7, oi = o_lin >> 3;
    const int mtile = xcd * (nmt >> 3) + oi / nnt;
    const int ntile = oi % nnt;
    const int m0 = mtile * 256, n0 = ntile * 256;

    f32x4 acc[8][4];
    #pragma unroll
    for (int i = 0; i < 8; i++)
        #pragma unroll
        for (int j = 0; j < 4; j++) { f32x4 z = {0.f, 0.f, 0.f, 0.f}; acc[i][j] = z; }

    // staging: per tile, A 256 rows x 4 segs = 1024 slots = 512 thr x 2; B same.
    // 4 gload_lds per thread per tile -> vmcnt counts 4/tile/wave.
    const unsigned short* gpa[2]; const unsigned short* gpb[2];
    unsigned short* lpa[2]; unsigned short* lpb[2];
    #pragma unroll
    for (int j = 0; j < 2; j++) {
        int c = j * 512 + tid;
        int r = c >> 2, slot = c & 3, kg = slot ^ (r & 3);   // 4-seg XOR swizzle
        gpa[j] = A + (size_t)(m0 + r) * K + kg * 8;
        gpb[j] = Bt + (size_t)(n0 + r) * K + kg * 8;
        lpa[j] = lds + (size_t)(j * 512 + w * 64) * 8;          // wave-uniform dest
        lpb[j] = lds + 8192 + (size_t)(j * 512 + w * 64) * 8;
    }
    auto stage = [&](int buf, int kt) {
        #pragma unroll
        for (int j = 0; j < 2; j++) gload_lds16(gpa[j] + kt * 32, lpa[j] + buf * 16384);
        #pragma unroll
        for (int j = 0; j < 2; j++) gload_lds16(gpb[j] + kt * 32, lpb[j] + buf * 16384);
    };

    // prologue: fill the 3-deep ring; wait only tile 0 (tiles 1,2 = 8 loads in flight)
    stage(0, 0); stage(1, 1); stage(2, 2);
    asm volatile("s_waitcnt vmcnt(8)" ::: "memory");
    __builtin_amdgcn_sched_barrier(0);
    __builtin_amdgcn_s_barrier();
    __builtin_amdgcn_sched_barrier(0);

    for (int t = 0; t < NT; ++t) {
        const unsigned short* ab = lds + (t % 3) * 16384;
        const unsigned short* bb = ab + 8192;
        bf16x8 af[8], bf[4];
        #pragma unroll
        for (int nf = 0; nf < 4; nf++) {
            int row = wn * 64 + nf * 16 + l15;
            bf[nf] = *(const bf16x8*)&bb[row * 32 + ((quad ^ (row & 3)) * 8)];
        }
        #pragma unroll
        for (int mf = 0; mf < 8; mf++) {
            int row = wm * 128 + mf * 16 + l15;
            af[mf] = *(const bf16x8*)&ab[row * 32 + ((quad ^ (row & 3)) * 8)];
        }
        __builtin_amdgcn_s_setprio(1);
        #pragma unroll
        for (int mf = 0; mf < 8; mf++)
            #pragma unroll
            for (int nf = 0; nf < 4; nf++)
                acc[mf][nf] = __builtin_amdgcn_mfma_f32_16x16x32_bf16(af[mf], bf[nf], acc[mf][nf], 0, 0, 0);
        __builtin_amdgcn_s_setprio(0);
        __builtin_amdgcn_sched_barrier(0);
        __builtin_amdgcn_s_barrier();          // all waves done reading buf t%3
        __builtin_amdgcn_sched_barrier(0);
        if (t < NT - 3) {
            stage(t % 3, t + 3);               // overwrite just-freed buffer
            asm volatile("s_waitcnt vmcnt(8)" ::: "memory");   // tile t+1 resident
        } else if (t == NT - 3) {
            asm volatile("s_waitcnt vmcnt(4)" ::: "memory");
        } else if (t == NT - 2) {
            asm volatile("s_waitcnt vmcnt(0)" ::: "memory");
        }
        __builtin_amdgcn_sched_barrier(0);
        __builtin_amdgcn_s_barrier();          // all waves see tile t+1
        __builtin_amdgcn_sched_barrier(0);
    }

    // ---- coalesced bounce epilogue (wave-private LDS scratch; r9-verified) ----
    float* sc = (float*)lds + w * (16 * 68);
    const int cbase = n0 + wn * 64;
    const int r2 = lane >> 2, c2 = (lane & 3) * 16;
    float4 bvv[4];
    #pragma unroll
    for (int i = 0; i < 4; i++) bvv[i] = *(const float4*)(bias + cbase + c2 + i * 4);
    #pragma unroll
    for (int mt = 0; mt < 8; mt++) {
        #pragma unroll
        for (int nt = 0; nt < 4; nt++)
            #pragma unroll
            for (int r = 0; r < 4; r++)
                sc[(quad * 4 + r) * 68 + nt * 16 + l15] = acc[mt][nt][r];
        const int row_g = m0 + wm * 128 + mt * 16 + r2;
        float v[16];
        #pragma unroll
        for (int i = 0; i < 4; i++) {
            float4 t = *(const float4*)&sc[r2 * 68 + c2 + i * 4];
            v[i * 4 + 0] = fmaxf(t.x + bvv[i].x, 0.f);
            v[i * 4 + 1] = fmaxf(t.y + bvv[i].y, 0.f);
            v[i * 4 + 2] = fmaxf(t.z + bvv[i].z, 0.f);
            v[i * 4 + 3] = fmaxf(t.w + bvv[i].w, 0.f);
        }
        unsigned short ob[16];
        #pragma unroll
        for (int i = 0; i < 16; i++) ob[i] = f2bf(v[i]);
        unsigned short* op = out_bf + (size_t)row_g * N + cbase + c2;
        *(u32x4*)op = *(const u32x4*)ob;
        *(u32x4*)(op + 8) = *(const u32x4*)(ob + 8);
    }
}

// ---------------- fused QK + V GEMM (z=0: qk row-major bf16; z=1: v transposed) --------
__global__ __launch_bounds__(256) void gemm_qkv_kernel(
    const unsigned short* __restrict__ x_bf, const unsigned short* __restrict__ y_bf,
    const unsigned short* __restrict__ wkT, const unsigned short* __restrict__ wvT,
    const float* __restrict__ bk, const float* __restrict__ bv,
    unsigned short* __restrict__ qk_out, unsigned short* __restrict__ vt_out) {
    constexpr int BN = 64, MT = 2, WROWS = 32, BRND = 2;
    constexpr int N = 512, K = 512;
    __shared__ unsigned short a_lds[128 * 64];
    __shared__ unsigned short b_lds[BN * 64];

    const bool isv = blockIdx.z != 0;
    const unsigned short* A  = isv ? y_bf : x_bf;
    const unsigned short* Bt = isv ? wvT : wkT;
    const float* bias        = isv ? bv : bk;

    const int tid = threadIdx.x;
    const int lane = tid & 63, wid = tid >> 6;
    const int l15 = lane & 15, quad = lane >> 4;
    const int nmt = gridDim.x, nnt = gridDim.y;
    const int o_lin = blockIdx.y * nmt + blockIdx.x;
    const int xcd = o_lin & 7, oi = o_lin >> 3;
    const int mtile = xcd * (nmt >> 3) + oi / nnt;
    const int ntile = oi % nnt;
    const int m0 = mtile * 128, n0 = ntile * BN;

    f32x4 acc[MT][4];
    #pragma unroll
    for (int i = 0; i < MT; i++)
        #pragma unroll
        for (int j = 0; j < 4; j++) { f32x4 z = {0.f, 0.f, 0.f, 0.f}; acc[i][j] = z; }

    const unsigned short* aP[4];
    unsigned short* aL[4];
    #pragma unroll
    for (int j = 0; j < 4; j++) {
        int c = wid * 256 + j * 64 + lane;
        int r = c >> 3, slot = c & 7, kg = slot ^ (r & 7);
        aP[j] = A + (size_t)(m0 + r) * K + kg * 8;
        aL[j] = a_lds + (size_t)(wid * 256 + j * 64) * 8;
    }
    const unsigned short* bP[BRND];
    unsigned short* bL[BRND];
    #pragma unroll
    for (int j = 0; j < BRND; j++) {
        int c = wid * (BRND * 64) + j * 64 + lane;
        int r = c >> 3, slot = c & 7, kg = slot ^ (r & 7);
        bP[j] = Bt + (size_t)(n0 + r) * K + kg * 8;
        bL[j] = b_lds + (size_t)(wid * (BRND * 64) + j * 64) * 8;
    }

    for (int k0 = 0; k0 < K; k0 += 64) {
        #pragma unroll
        for (int j = 0; j < 4; j++) gload_lds16(aP[j] + k0, aL[j]);
        #pragma unroll
        for (int j = 0; j < BRND; j++) gload_lds16(bP[j] + k0, bL[j]);
        __syncthreads();

        bf16x8 af[MT][2], bfv[4][2];
        #pragma unroll
        for (int mt = 0; mt < MT; mt++) {
            int row = wid * WROWS + mt * 16 + l15;
            #pragma unroll
            for (int kh = 0; kh < 2; kh++)
                af[mt][kh] = *(const bf16x8*)&a_lds[row * 64 + (((kh * 4 + quad) ^ (row & 7)) * 8)];
        }
        #pragma unroll
        for (int nt = 0; nt < 4; nt++) {
            int row = nt * 16 + l15;
            #pragma unroll
            for (int kh = 0; kh < 2; kh++)
                bfv[nt][kh] = *(const bf16x8*)&b_lds[row * 64 + (((kh * 4 + quad) ^ (row & 7)) * 8)];
        }
        #pragma unroll
        for (int mt = 0; mt < MT; mt++)
            #pragma unroll
            for (int nt = 0; nt < 4; nt++) {
                acc[mt][nt] = __builtin_amdgcn_mfma_f32_16x16x32_bf16(af[mt][0], bfv[nt][0], acc[mt][nt], 0, 0, 0);
                acc[mt][nt] = __builtin_amdgcn_mfma_f32_16x16x32_bf16(af[mt][1], bfv[nt][1], acc[mt][nt], 0, 0, 0);
            }
        __syncthreads();
    }

    #pragma unroll
    for (int nt = 0; nt < 4; nt++) {
        int col = n0 + nt * 16 + l15;
        float bv_ = bias[col];
        #pragma unroll
        for (int mt = 0; mt < MT; mt++) {
            int row0 = m0 + wid * WROWS + mt * 16 + quad * 4;
            ushort4 o;
            o.x = f2bf(acc[mt][nt][0] + bv_);
            o.y = f2bf(acc[mt][nt][1] + bv_);
            o.z = f2bf(acc[mt][nt][2] + bv_);
            o.w = f2bf(acc[mt][nt][3] + bv_);
            if (isv) {
                int hh = col >> 6, d = col & 63;
                int bb = row0 >> 10, s0 = row0 & 1023;
                *(ushort4*)(vt_out + ((size_t)(bb * H + hh) * DK + d) * S + s0) = o;
            } else {
                #pragma unroll
                for (int r = 0; r < 4; r++)
                    qk_out[(size_t)(row0 + r) * N + col] =
                        (r == 0) ? o.x : (r == 1) ? o.y : (r == 2) ? o.z : o.w;
            }
        }
    }
}

// ---------------- LayerNorm over D=512, one block per row ----------------
__global__ __launch_bounds__(256) void ln_kernel(
    const float* __restrict__ in, const float* __restrict__ gamma,
    const float* __restrict__ beta, float* __restrict__ out_f32,
    unsigned short* __restrict__ out_bf) {
    __shared__ float red[8];
    int row = blockIdx.x, tid = threadIdx.x;
    const float* p = in + (size_t)row * D;
    float2 v = *(const float2*)(p + tid * 2);
    float s = v.x + v.y;
    float q = v.x * v.x + v.y * v.y;
    #pragma unroll
    for (int off = 32; off > 0; off >>= 1) {
        s += __shfl_xor(s, off);
        q += __shfl_xor(q, off);
    }
    int wid = tid >> 6, lane = tid & 63;
    if (lane == 0) { red[wid] = s; red[4 + wid] = q; }
    __syncthreads();
    s = red[0] + red[1] + red[2] + red[3];
    q = red[4] + red[5] + red[6] + red[7];
    float mean = s * (1.f / D);
    float var = q * (1.f / D) - mean * mean;
    float inv = rsqrtf(var + 1e-5f);
    int c = tid * 2;
    float2 g = *(const float2*)(gamma + c);
    float2 bb = *(const float2*)(beta + c);
    float o0 = (v.x - mean) * inv * g.x + bb.x;
    float o1 = (v.y - mean) * inv * g.y + bb.y;
    *(float2*)(out_f32 + (size_t)row * D + c) = make_float2(o0, o1);
    ushort2 ob; ob.x = f2bf(o0); ob.y = f2bf(o1);
    *(ushort2*)(out_bf + (size_t)row * D + c) = ob;
}

// ---------------- Flash attention: 4-wave blocks, LDS-shared K/V, no split-K --------
__global__ __launch_bounds__(256, 2) void attn_kernel(
    const unsigned short* __restrict__ qk, const unsigned short* __restrict__ vt,
    unsigned short* __restrict__ ob) {
    __shared__ unsigned short kbuf[2][64 * 64];
    __shared__ unsigned short vbuf[2][64 * 64];
    __shared__ unsigned p_u32[4][32 * 36];     // per-wave P (32 dwords + 4 pad per row)
    constexpr float C = 0.18033688011112042f;  // log2(e)/8
    const float NEGINF = -__builtin_huge_valf();

    const int bx = blockIdx.x;
    const int Qb = 7 - (bx >> 6);              // heavy q-blocks first
    const int hh = bx & 63;
    const int b = hh >> 3, h = hh & 7;         // XCD = bx%8 = h -> 2MB K/V set per XCD
    const int head = hh;
    const int tid = threadIdx.x;
    const int w = tid >> 6, lane = tid & 63;
    const int l15 = lane & 15, quad = lane >> 4;

    const int nkt = 2 * Qb + 2;                // causal k-tiles for this q-block
    const int qrow0 = Qb * 128 + w * 32;       // wave's first q-row

    const int rowbase = b * S, colbase = h * DK;
    const unsigned short* kbase = qk + (size_t)rowbase * D + colbase;
    const unsigned short* vbase = vt + (size_t)head * (DK * S);

    bf16x8 qf[2][2];
    #pragma unroll
    for (int u = 0; u < 2; u++) {
        const unsigned short* qrow =
            qk + (size_t)(rowbase + qrow0 + u * 16 + l15) * D + colbase;
        qf[u][0] = *(const bf16x8*)(qrow + quad * 8);
        qf[u][1] = *(const bf16x8*)(qrow + 32 + quad * 8);
    }

    // staging lane map: 8 lanes/row, XOR-swizzled source seg so LDS stays linear
    const int sr = lane >> 3;
    const int sseg = (lane & 7) ^ sr;
    const unsigned short* kgp[2]; const unsigned short* vgp[2];
    unsigned short* kld[2]; unsigned short* vld[2];
    #pragma unroll
    for (int j = 0; j < 2; j++) {
        int rt = w * 16 + j * 8 + sr;
        kgp[j] = kbase + (size_t)rt * D + sseg * 8;
        vgp[j] = vbase + (size_t)rt * S + sseg * 8;
        kld[j] = &kbuf[0][(w * 16 + j * 8) * 64];   // wave-uniform
        vld[j] = &vbuf[0][(w * 16 + j * 8) * 64];
    }
    auto stage = [&](int buf, int kt) {
        #pragma unroll
        for (int j = 0; j < 2; j++) gload_lds16(kgp[j] + (size_t)kt * 64 * D, kld[j] + buf * 4096);
        #pragma unroll
        for (int j = 0; j < 2; j++) gload_lds16(vgp[j] + kt * 64, vld[j] + buf * 4096);
    };

    float l_r[2] = {0.f, 0.f};
    f32x4 o_acc[2][4];
    #pragma unroll
    for (int u = 0; u < 2; u++)
        #pragma unroll
        for (int i = 0; i < 4; i++) { f32x4 z = {0.f, 0.f, 0.f, 0.f}; o_acc[u][i] = z; }

    auto consume = [&](int kt, const unsigned short* kl, const unsigned short* vl) {
        unsigned* pb = p_u32[w];
        bf16x8 kf[4][2];
        #pragma unroll
        for (int mt = 0; mt < 4; mt++) {
            const unsigned short* kr = kl + (mt * 16 + l15) * 64;
            #pragma unroll
            for (int kh = 0; kh < 2; kh++)
                kf[mt][kh] = *(const bf16x8*)(kr + (((kh * 4 + quad) ^ (l15 & 7)) * 8));
        }
        const bool diag = kt * 64 + 64 > qrow0;
        #pragma unroll
        for (int u = 0; u < 2; u++) {
            const int qb = qrow0 + u * 16;
            const int ql = u * 16 + l15;
            #pragma unroll
            for (int mt = 0; mt < 4; mt++) {
                if (kt * 64 + mt * 16 < qb + 16) {
                    f32x4 a = {0.f, 0.f, 0.f, 0.f};
                    a = __builtin_amdgcn_mfma_f32_16x16x32_bf16(kf[mt][0], qf[u][0], a, 0, 0, 0);
                    a = __builtin_amdgcn_mfma_f32_16x16x32_bf16(kf[mt][1], qf[u][1], a, 0, 0, 0);
                    if (diag) {
                        const int gi = qb + l15;
                        #pragma unroll
                        for (int r = 0; r < 4; r++) {
                            int gj = kt * 64 + mt * 16 + quad * 4 + r;
                            a[r] = (gj >= gi) ? NEGINF : a[r];
                        }
                    }
                    float e0 = exp2f(a[0] * C), e1 = exp2f(a[1] * C);
                    float e2 = exp2f(a[2] * C), e3 = exp2f(a[3] * C);
                    unsigned pk0, pk1;
                    asm("v_cvt_pk_bf16_f32 %0, %1, %2" : "=v"(pk0) : "v"(e0), "v"(e1));
                    asm("v_cvt_pk_bf16_f32 %0, %1, %2" : "=v"(pk1) : "v"(e2), "v"(e3));
                    l_r[u] += (e0 + e1) + (e2 + e3);
                    *(uint2*)&pb[ql * 36 + mt * 8 + quad * 2] = make_uint2(pk0, pk1);
                } else {
                    *(uint2*)&pb[ql * 36 + mt * 8 + quad * 2] = make_uint2(0u, 0u);
                }
            }
        }
        bf16x8 vf[4][2];
        #pragma unroll
        for (int mt = 0; mt < 4; mt++) {
            const unsigned short* vr = vl + (mt * 16 + l15) * 64;
            #pragma unroll
            for (int kh = 0; kh < 2; kh++)
                vf[mt][kh] = *(const bf16x8*)(vr + (((kh * 4 + quad) ^ (l15 & 7)) * 8));
        }
        #pragma unroll
        for (int u = 0; u < 2; u++) {
            const int qb = qrow0 + u * 16;
            const int ql = u * 16 + l15;
            u32x4 d0 = *(const u32x4*)&pb[ql * 36 + quad * 4];
            bf16x8 pb0 = __builtin_bit_cast(bf16x8, d0);
            const bool hi = (kt * 64 + 32 < qb + 16);
            if (hi) {
                u32x4 d1 = *(const u32x4*)&pb[ql * 36 + 16 + quad * 4];
                bf16x8 pb1 = __builtin_bit_cast(bf16x8, d1);
                #pragma unroll
                for (int mt = 0; mt < 4; mt++) {
                    o_acc[u][mt] = __builtin_amdgcn_mfma_f32_16x16x32_bf16(vf[mt][0], pb0, o_acc[u][mt], 0, 0, 0);
                    o_acc[u][mt] = __builtin_amdgcn_mfma_f32_16x16x32_bf16(vf[mt][1], pb1, o_acc[u][mt], 0, 0, 0);
                }
            } else {
                #pragma unroll
                for (int mt = 0; mt < 4; mt++)
                    o_acc[u][mt] = __builtin_amdgcn_mfma_f32_16x16x32_bf16(vf[mt][0], pb0, o_acc[u][mt], 0, 0, 0);
            }
        }
    };

    stage(0, 0);
    for (int kt = 0; kt < nkt; ++kt) {
        const int cur = kt & 1;
        if (kt + 1 < nkt) {
            stage(cur ^ 1, kt + 1);
            asm volatile("s_waitcnt vmcnt(4)" ::: "memory");   // cur's 4 loads done, next 4 in flight
        } else {
            asm volatile("s_waitcnt vmcnt(0)" ::: "memory");
        }
        __builtin_amdgcn_sched_barrier(0);
        __builtin_amdgcn_s_barrier();
        __builtin_amdgcn_sched_barrier(0);
        if (kt * 64 < qrow0 + 32)              // skip fully-masked tiles (still barrier)
            consume(kt, &kbuf[cur][0], &vbuf[cur][0]);
        __builtin_amdgcn_sched_barrier(0);
        __builtin_amdgcn_s_barrier();          // all waves done reading before overwrite
        __builtin_amdgcn_sched_barrier(0);
    }

    // full-row l across quads, then write normalized bf16 O directly
    #pragma unroll
    for (int u = 0; u < 2; u++) {
        l_r[u] += __shfl_xor(l_r[u], 16);
        l_r[u] += __shfl_xor(l_r[u], 32);
    }
    #pragma unroll
    for (int u = 0; u < 2; u++) {
        const int si = qrow0 + u * 16 + l15;
        float inv = (l_r[u] > 0.f) ? 1.f / l_r[u] : 0.f;
        if (si == 0) inv = 0.f;   // row_keep
        unsigned short* orow = ob + (size_t)(b * S + si) * D + h * DK;
        #pragma unroll
        for (int mt = 0; mt < 4; mt++) {
            ushort4 o;
            o.x = f2bf(o_acc[u][mt][0] * inv);
            o.y = f2bf(o_acc[u][mt][1] * inv);
            o.z = f2bf(o_acc[u][mt][2] * inv);
            o.w = f2bf(o_acc[u][mt][3] * inv);
            *(ushort4*)(orow + mt * 16 + quad * 4) = o;
        }
    }
}

// ---------------- driver ----------------
extern "C" void kernel_launch(void* const* d_in, const int* in_sizes, int n_in,
                              void* d_out, int out_size, void* d_ws, size_t ws_size,
                              hipStream_t stream) {
    (void)in_sizes; (void)n_in; (void)out_size; (void)ws_size;
    const float* qe  = (const float*)d_in[0];
    const float* qa  = (const float*)d_in[1];
    const float* pe  = (const float*)d_in[2];
    const float* Wk  = (const float*)d_in[3];
    const float* bk  = (const float*)d_in[4];
    const float* Wv  = (const float*)d_in[5];
    const float* bv  = (const float*)d_in[6];
    const float* Wo  = (const float*)d_in[7];
    const float* bo  = (const float*)d_in[8];
    const float* l1s = (const float*)d_in[9];
    const float* l1b = (const float*)d_in[10];
    const float* W1  = (const float*)d_in[11];
    const float* b1  = (const float*)d_in[12];
    const float* W2  = (const float*)d_in[13];
    const float* b2  = (const float*)d_in[14];
    const float* l2s = (const float*)d_in[15];
    const float* l2b = (const float*)d_in[16];

    char* w = (char*)d_ws;
    float* x_f32  = (float*)w;           w += (size_t)MR * D * 4;
    float* t_f32  = (float*)w;           w += (size_t)MR * D * 4;
    float* x1_f32 = (float*)w;           w += (size_t)MR * D * 4;
    unsigned short* x_bf  = (unsigned short*)w; w += (size_t)MR * D * 2;
    unsigned short* y_bf  = (unsigned short*)w; w += (size_t)MR * D * 2;
    unsigned short* qk_bf = (unsigned short*)w; w += (size_t)MR * D * 2;
    unsigned short* vt_bf = (unsigned short*)w; w += (size_t)MR * D * 2;  // V^T [B,H,DK,S]
    unsigned short* o_bf  = (unsigned short*)w; w += (size_t)MR * D * 2;
    unsigned short* x1_bf = (unsigned short*)w; w += (size_t)MR * D * 2;
    unsigned short* h_bf  = (unsigned short*)w; w += (size_t)MR * DFF * 2;
    unsigned short* wkT = (unsigned short*)w;   w += (size_t)L * D * D * 2;
    unsigned short* wvT = (unsigned short*)w;   w += (size_t)L * D * D * 2;
    unsigned short* woT = (unsigned short*)w;   w += (size_t)L * D * D * 2;
    unsigned short* w1T = (unsigned short*)w;   w += (size_t)L * D * DFF * 2;
    unsigned short* w2T = (unsigned short*)w;   w += (size_t)L * DFF * D * 2;

    add_pe_kernel<<<MR * D / 4 / 256, 256, 0, stream>>>(qe, qa, pe, x_f32, x_bf, y_bf);
    wtrans_kernel<<<dim3(8, 8, L), 256, 0, stream>>>(Wk, wkT, D, D);
    wtrans_kernel<<<dim3(8, 8, L), 256, 0, stream>>>(Wv, wvT, D, D);
    wtrans_kernel<<<dim3(8, 8, L), 256, 0, stream>>>(Wo, woT, D, D);
    wtrans_kernel<<<dim3(32, 8, L), 256, 0, stream>>>(W1, w1T, D, DFF);
    wtrans_kernel<<<dim3(8, 32, L), 256, 0, stream>>>(W2, w2T, DFF, D);

    dim3 g512(64, 8);
    for (int l = 0; l < L; l++) {
        gemm_qkv_kernel<<<dim3(64, 8, 2), 256, 0, stream>>>(
            x_bf, y_bf, wkT + (size_t)l * D * D, wvT + (size_t)l * D * D,
            bk + l * D, bv + l * D, qk_bf, vt_bf);
        attn_kernel<<<512, 256, 0, stream>>>(qk_bf, vt_bf, o_bf);
        gemm_kernel<64, false, true, true, false, false><<<g512, 256, 0, stream>>>(
            o_bf, woT + (size_t)l * D * D, bo + l * D, x_f32, t_f32, nullptr, MR, D, D);
        ln_kernel<<<MR, 256, 0, stream>>>(t_f32, l1s + l * D, l1b + l * D, x1_f32, x1_bf);
        ffn1_kernel<<<dim3(32, 8), 512, 0, stream>>>(
            x1_bf, w1T + (size_t)l * D * DFF, b1 + l * DFF, h_bf);
        gemm_kernel<64, false, true, true, false, false><<<g512, 256, 0, stream>>>(
            h_bf, w2T + (size_t)l * DFF * D, b2 + l * D, x1_f32, t_f32, nullptr, MR, D, DFF);
        float* xo = (l == L - 1) ? (float*)d_out : x_f32;
        ln_kernel<<<MR, 256, 0, stream>>>(t_f32, l2s + l * D, l2b + l * D, xo, x_bf);
    }
}